// Round 4
// baseline (146.815 us; speedup 1.0000x reference)
//
#include <hip/hip_runtime.h>
#include <stdint.h>
#include <math.h>

typedef unsigned short u16;

// Problem constants (B=16, N=M=4096, D=3)
#define NPTS  4096
#define NB    16
#define NRES  12288               // residuals per (batch, direction)
#define NPAIR 32                  // 16 batches x 2 directions
#define G     16                  // grid cells per axis
#define NCELL 4096                // G^3
#define HCEL  0.0625f             // 1/G
#define SSTR  4160                // starts stride (u16 elems, >= 4097)
#define MARGIN 1e-5f
// 0-indexed order-statistic ranks for jnp.quantile(0.15/0.85, linear)
#define RANK_LO 1843u
#define RANK_HI 10443u

__device__ __forceinline__ uint32_t f2key(float f) {
    uint32_t u = __float_as_uint(f);
    return (u & 0x80000000u) ? ~u : (u | 0x80000000u);
}
__device__ __forceinline__ float key2f(uint32_t k) {
    uint32_t u = (k & 0x80000000u) ? (k ^ 0x80000000u) : ~k;
    return __uint_as_float(u);
}

// ---------------------------------------------------------------------------
// Kernel 1: build — counting-sort each pairdir's targets into 16^3 cells.
// 32 blocks x 256 threads. Outputs: arrA {-2x,-2y,-2z,|t|^2}, starts, idx16.
// ---------------------------------------------------------------------------
__global__ __launch_bounds__(256) void build_kernel(const float* __restrict__ x,
                                                    const float* __restrict__ y,
                                                    float4* __restrict__ arrA,
                                                    u16* __restrict__ starts,
                                                    u16* __restrict__ idx16) {
    __shared__ uint32_t hist[NCELL];          // 16 KB
    __shared__ u16 cells[NPTS];               // 8 KB
    __shared__ uint32_t wpart[4];
    const int pd = blockIdx.x, b = pd >> 1, dir = pd & 1;
    const float* t = (dir == 0 ? y : x) + (size_t)b * NPTS * 3;
    const int tid = threadIdx.x, lane = tid & 63, wv = tid >> 6;

    #pragma unroll
    for (int j = 0; j < 16; ++j) hist[tid * 16 + j] = 0u;
    __syncthreads();

    // phase 1: cells + histogram (16 targets/thread, contiguous)
    {
        const float4* tp = reinterpret_cast<const float4*>(t + (size_t)tid * 48);
        float f[48];
        #pragma unroll
        for (int j = 0; j < 12; ++j) {
            const float4 v = tp[j];
            f[j * 4 + 0] = v.x; f[j * 4 + 1] = v.y; f[j * 4 + 2] = v.z; f[j * 4 + 3] = v.w;
        }
        #pragma unroll
        for (int k = 0; k < 16; ++k) {
            const int cx = (int)(f[k * 3 + 0] * 16.f);
            const int cy = (int)(f[k * 3 + 1] * 16.f);
            const int cz = (int)(f[k * 3 + 2] * 16.f);
            const int c = (cx * G + cy) * G + cz;
            cells[tid * 16 + k] = (u16)c;
            atomicAdd(&hist[c], 1u);
        }
    }
    __syncthreads();

    // phase 2: exclusive scan of 4096 bins (16/thread)
    {
        uint32_t loc[16], sum = 0;
        const int base = tid * 16;
        #pragma unroll
        for (int j = 0; j < 16; ++j) { loc[j] = hist[base + j]; sum += loc[j]; }
        uint32_t sc = sum;
        #pragma unroll
        for (int off = 1; off < 64; off <<= 1) {
            const uint32_t u = __shfl_up(sc, off);
            if (lane >= off) sc += u;
        }
        if (lane == 63) wpart[wv] = sc;
        __syncthreads();
        uint32_t wbase = 0;
        #pragma unroll
        for (int k = 0; k < 4; ++k) wbase += (k < wv) ? wpart[k] : 0u;
        uint32_t ex = wbase + sc - sum;
        #pragma unroll
        for (int j = 0; j < 16; ++j) { hist[base + j] = ex; ex += loc[j]; }
    }
    __syncthreads();

    // write starts (exclusive prefix; [4096] = total)
    for (int i = tid; i <= NCELL; i += 256)
        starts[(size_t)pd * SSTR + i] = (u16)((i == NCELL) ? NPTS : hist[i]);
    __syncthreads();

    // phase 3: scatter (order within cell arbitrary; ties resolved by idx16)
    {
        const float4* tp = reinterpret_cast<const float4*>(t + (size_t)tid * 48);
        float f[48];
        #pragma unroll
        for (int j = 0; j < 12; ++j) {
            const float4 v = tp[j];
            f[j * 4 + 0] = v.x; f[j * 4 + 1] = v.y; f[j * 4 + 2] = v.z; f[j * 4 + 3] = v.w;
        }
        #pragma unroll
        for (int k = 0; k < 16; ++k) {
            const float px = f[k * 3 + 0], py = f[k * 3 + 1], pz = f[k * 3 + 2];
            const int c = cells[tid * 16 + k];
            const uint32_t pos = atomicAdd(&hist[c], 1u);
            const float w = fmaf(pz, pz, fmaf(py, py, px * px));
            arrA[(size_t)pd * NPTS + pos] = make_float4(-2.f * px, -2.f * py, -2.f * pz, w);
            idx16[(size_t)pd * NPTS + pos] = (u16)(tid * 16 + k);
        }
    }
}

// ---------------------------------------------------------------------------
// Kernel 2: grid NN + residual keys. grid=(16 qblocks, 32 pairdirs) x 256.
// Queries of pd are the sorted targets of pd^1 (cell-sorted -> low divergence,
// L1-resident candidate gathers). Emits keys, global level-1 hist, partials.
// ---------------------------------------------------------------------------
__global__ __launch_bounds__(256, 4) void query_kernel(const float4* __restrict__ arrA,
                                                       const u16* __restrict__ starts,
                                                       const u16* __restrict__ idx16,
                                                       uint32_t* __restrict__ keys,
                                                       uint32_t* __restrict__ histg,
                                                       double* __restrict__ partials) {
    __shared__ double wred[8];
    const int pd = blockIdx.y;
    const int tid = threadIdx.x, lane = tid & 63, wv = tid >> 6;
    const int p = blockIdx.x * 256 + tid;      // sorted query position

    const float4* __restrict__ tp = arrA + (size_t)pd * NPTS;
    const u16* __restrict__ st = starts + (size_t)pd * SSTR;
    const u16* __restrict__ ixp = idx16 + (size_t)pd * NPTS;

    const float4 Q = arrA[(size_t)(pd ^ 1) * NPTS + p];
    const float qx = -0.5f * Q.x, qy = -0.5f * Q.y, qz = -0.5f * Q.z;
    const float qq = Q.w;                      // |q|^2 (for shell bound only)
    const int cx = (int)(qx * 16.f), cy = (int)(qy * 16.f), cz = (int)(qz * 16.f);

    float best = 3.0e38f;
    int bpos = 0;
    uint32_t bidx = 0xFFFFFFFFu;

    #define SCAN_RUN(A_, E_)                                                     \
        for (int p2 = (A_); p2 < (E_); ++p2) {                                   \
            const float4 T = tp[p2];                                             \
            const float d = fmaf(qx, T.x, fmaf(qy, T.y, fmaf(qz, T.z, T.w)));    \
            if (d < best) { best = d; bpos = p2; bidx = ixp[p2]; }               \
            else if (d == best) {                                                \
                const uint32_t ci = ixp[p2];                                     \
                if (ci < bidx) { bidx = ci; bpos = p2; }                         \
            }                                                                    \
        }

    {   // Chebyshev <=1 block (27 cells, z-contiguous runs)
        const int xlo = max(cx - 1, 0), xhi = min(cx + 1, G - 1);
        const int ylo = max(cy - 1, 0), yhi = min(cy + 1, G - 1);
        const int zlo = max(cz - 1, 0), zhi = min(cz + 1, G - 1);
        for (int ix = xlo; ix <= xhi; ++ix)
            for (int iy = ylo; iy <= yhi; ++iy) {
                const int c0 = (ix * G + iy) * G;
                const int a = st[c0 + zlo], e = st[c0 + zhi + 1];
                SCAN_RUN(a, e)
            }
    }
    // expand shells while min possible distance could beat current best
    for (int s = 2; s <= G - 1; ++s) {
        const float dmin = (float)(s - 1) * HCEL;
        if (fmaf(dmin, dmin, -(best + qq)) > MARGIN) break;
        for (int dx = -s; dx <= s; ++dx) {
            const int ix = cx + dx;
            if (ix < 0 || ix > G - 1) continue;
            const int adx = dx < 0 ? -dx : dx;
            for (int dy = -s; dy <= s; ++dy) {
                const int iy = cy + dy;
                if (iy < 0 || iy > G - 1) continue;
                const int ady = dy < 0 ? -dy : dy;
                const int c0 = (ix * G + iy) * G;
                if (max(adx, ady) == s) {       // full z range
                    const int zlo = max(cz - s, 0), zhi = min(cz + s, G - 1);
                    const int a = st[c0 + zlo], e = st[c0 + zhi + 1];
                    SCAN_RUN(a, e)
                } else {                        // only z = cz +/- s
                    const int z1 = cz - s;
                    if (z1 >= 0) { const int a = st[c0 + z1], e = st[c0 + z1 + 1]; SCAN_RUN(a, e) }
                    const int z2 = cz + s;
                    if (z2 <= G - 1) { const int a = st[c0 + z2], e = st[c0 + z2 + 1]; SCAN_RUN(a, e) }
                }
            }
        }
    }
    #undef SCAN_RUN

    // residuals (exact: -0.5 * (-2t) == t bitwise)
    const float4 T = tp[bpos];
    const float rx = qx - (-0.5f * T.x);
    const float ry = qy - (-0.5f * T.y);
    const float rz = qz - (-0.5f * T.z);
    const uint32_t k0 = f2key(rx), k1 = f2key(ry), k2 = f2key(rz);
    uint32_t* kp = keys + (size_t)pd * NRES + (size_t)p * 3;
    kp[0] = k0; kp[1] = k1; kp[2] = k2;
    uint32_t* hp = histg + (size_t)pd * 2048;
    atomicAdd(&hp[k0 >> 21], 1u);
    atomicAdd(&hp[k1 >> 21], 1u);
    atomicAdd(&hp[k2 >> 21], 1u);

    // f64 partial sums for fallback std
    double s1 = (double)rx + (double)ry + (double)rz;
    double s2 = (double)rx * rx + (double)ry * ry + (double)rz * rz;
    #pragma unroll
    for (int off = 32; off; off >>= 1) { s1 += __shfl_down(s1, off); s2 += __shfl_down(s2, off); }
    if (lane == 0) { wred[wv] = s1; wred[4 + wv] = s2; }
    __syncthreads();
    if (tid == 0) {
        double a = 0.0, c = 0.0;
        for (int k = 0; k < 4; ++k) { a += wred[k]; c += wred[4 + k]; }
        partials[(size_t)pd * 32 + blockIdx.x * 2 + 0] = a;
        partials[(size_t)pd * 32 + blockIdx.x * 2 + 1] = c;
    }
}

// ---------------------------------------------------------------------------
// Kernel 3: robust masked std. 32 blocks x 512 threads; keys from ws into
// registers (24/thread); level-1 hist pre-built; radix levels 2/3 in LDS.
// ---------------------------------------------------------------------------
#define STH 512

__device__ __forceinline__ void scan2048(uint32_t* h, uint32_t* wtmp) {
    const int tid = threadIdx.x, lane = tid & 63, wv = tid >> 6;
    const int i = tid * 4;
    const uint32_t a0 = h[i], a1 = h[i + 1], a2 = h[i + 2], a3 = h[i + 3];
    const uint32_t v = a0 + a1 + a2 + a3;
    uint32_t sc = v;
    #pragma unroll
    for (int off = 1; off < 64; off <<= 1) {
        const uint32_t u = __shfl_up(sc, off);
        if (lane >= off) sc += u;
    }
    if (lane == 63) wtmp[wv] = sc;
    __syncthreads();
    uint32_t base = 0;
    #pragma unroll
    for (int k = 0; k < 8; ++k) base += (k < wv) ? wtmp[k] : 0u;
    const uint32_t ex = base + sc - v;
    h[i] = ex; h[i + 1] = ex + a0; h[i + 2] = ex + a0 + a1; h[i + 3] = ex + a0 + a1 + a2;
    __syncthreads();
}

__device__ __forceinline__ int ubin(const uint32_t* cum, int n, uint32_t r) {
    int lo = 0, hi = n - 1;                    // largest b with cum[b] <= r
    while (lo < hi) {
        const int mid = (lo + hi + 1) >> 1;
        if (cum[mid] <= r) lo = mid; else hi = mid - 1;
    }
    return lo;
}

__global__ __launch_bounds__(512) void sigma_kernel(const uint32_t* __restrict__ keysg,
                                                    const uint32_t* __restrict__ histg,
                                                    const double* __restrict__ partials,
                                                    float* __restrict__ sig) {
    __shared__ uint32_t hist[4096];            // 16 KB
    __shared__ uint32_t wtmp[8];
    __shared__ double dred[16];
    __shared__ int ired[16];
    __shared__ uint32_t umin[16];
    __shared__ uint32_t bc[8];

    const int pair = blockIdx.x;
    const int tid = threadIdx.x, lane = tid & 63, wv = tid >> 6;

    // keys into registers (coalesced)
    uint32_t key[24];
    const uint32_t* kp = keysg + (size_t)pair * NRES;
    #pragma unroll
    for (int e = 0; e < 24; ++e) key[e] = kp[e * STH + tid];

    // full sums from f64 partials
    double S = 0.0, S2 = 0.0;
    {
        const double* pp = partials + (size_t)pair * 32;
        for (int k = 0; k < 16; ++k) { S += pp[2 * k]; S2 += pp[2 * k + 1]; }
    }
    const double mu = S / NRES;
    const double var_all = (S2 - S * mu) / (NRES - 1);
    const double sd = sqrt(var_all > 0.0 ? var_all : 0.0);

    // ---- Level 1: load pre-built 11-bit histogram, scan ----
    {
        const uint32_t* hg = histg + (size_t)pair * 2048;
        #pragma unroll
        for (int j = 0; j < 4; ++j) hist[tid * 4 + j] = hg[tid * 4 + j];
    }
    __syncthreads();
    scan2048(hist, wtmp);
    if (tid < 2) {
        const uint32_t r = tid ? RANK_HI : RANK_LO;
        const int bb = ubin(hist, 2048, r);
        bc[tid * 4 + 0] = (uint32_t)bb;
        bc[tid * 4 + 1] = r - hist[bb];
    }
    __syncthreads();

    // ---- Level 2: two concurrent 11-bit histograms ----
    const uint32_t pA1 = bc[0], rA1 = bc[1], pB1 = bc[4], rB1 = bc[5];
    #pragma unroll
    for (int j = 0; j < 8; ++j) hist[tid * 8 + j] = 0u;
    __syncthreads();
    #pragma unroll
    for (int e = 0; e < 24; ++e) {
        const uint32_t k = key[e];
        const uint32_t pfx = k >> 21, bin = (k >> 10) & 2047u;
        if (pfx == pA1) atomicAdd(&hist[bin], 1u);
        if (pfx == pB1) atomicAdd(&hist[2048 + bin], 1u);
    }
    __syncthreads();
    scan2048(hist, wtmp);
    scan2048(hist + 2048, wtmp);
    if (tid < 2) {
        const uint32_t* h = hist + tid * 2048;
        const uint32_t pfx = tid ? pB1 : pA1;
        const uint32_t r = tid ? rB1 : rA1;
        const int bb = ubin(h, 2048, r);
        bc[tid * 4 + 0] = (pfx << 11) | (uint32_t)bb;
        bc[tid * 4 + 1] = r - h[bb];
    }
    __syncthreads();

    // ---- Level 3: two concurrent 10-bit histograms -> exact keys ----
    const uint32_t pA2 = bc[0], rA2 = bc[1], pB2 = bc[4], rB2 = bc[5];
    #pragma unroll
    for (int j = 0; j < 8; ++j) hist[tid * 8 + j] = 0u;
    __syncthreads();
    #pragma unroll
    for (int e = 0; e < 24; ++e) {
        const uint32_t k = key[e];
        if ((k >> 10) == pA2) atomicAdd(&hist[k & 1023u], 1u);
        if ((k >> 10) == pB2) atomicAdd(&hist[2048 + (k & 1023u)], 1u);
    }
    __syncthreads();
    scan2048(hist, wtmp);
    scan2048(hist + 2048, wtmp);
    if (tid < 2) {
        const uint32_t* h = hist + tid * 2048;
        const uint32_t pfx = tid ? pB2 : pA2;
        const uint32_t r = tid ? rB2 : rA2;
        const uint32_t rtot = tid ? RANK_HI : RANK_LO;
        const int bb = ubin(h, 1024, r);
        const uint32_t k0 = (pfx << 10) | (uint32_t)bb;
        const uint32_t abs_le = (rtot - r) + h[bb + 1];
        bc[tid * 4 + 0] = k0;
        bc[tid * 4 + 1] = (abs_le >= rtot + 2u) ? 1u : 0u;   // rank+1 shares key?
    }
    __syncthreads();

    // ---- rank+1 keys: duplicate-covered or min key strictly greater ----
    const uint32_t k0 = bc[0], dup1 = bc[1], k2 = bc[4], dup3 = bc[5];
    uint32_t m1 = 0xFFFFFFFFu, m3 = 0xFFFFFFFFu;
    #pragma unroll
    for (int e = 0; e < 24; ++e) {
        const uint32_t k = key[e];
        if (k > k0 && k < m1) m1 = k;
        if (k > k2 && k < m3) m3 = k;
    }
    {
        uint32_t a = m1, c = m3;
        #pragma unroll
        for (int off = 32; off; off >>= 1) {
            const uint32_t ua = __shfl_down(a, off), uc = __shfl_down(c, off);
            a = (ua < a) ? ua : a; c = (uc < c) ? uc : c;
        }
        if (lane == 0) { umin[wv] = a; umin[8 + wv] = c; }
    }
    __syncthreads();
    uint32_t m1r = 0xFFFFFFFFu, m3r = 0xFFFFFFFFu;
    for (int k = 0; k < 8; ++k) {
        m1r = (umin[k] < m1r) ? umin[k] : m1r;
        m3r = (umin[8 + k] < m3r) ? umin[8 + k] : m3r;
    }
    const uint32_t k1 = dup1 ? k0 : m1r;
    const uint32_t k3 = dup3 ? k2 : m3r;

    // Linear-interpolated quantiles
    const double vl0 = (double)key2f(k0), vl1 = (double)key2f(k1);
    const double vh0 = (double)key2f(k2), vh1 = (double)key2f(k3);
    const double fr_lo = 0.15 * (NRES - 1) - (double)RANK_LO;
    const double fr_hi = 0.85 * (NRES - 1) - (double)RANK_HI;
    const float q_lo = (float)(vl0 + fr_lo * (vl1 - vl0));
    const float q_hi = (float)(vh0 + fr_hi * (vh1 - vh0));

    // Pass B: counts + sums under both predicates
    int cq = 0, cs = 0;
    double sq = 0.0, ss = 0.0;
    #pragma unroll
    for (int e = 0; e < 24; ++e) {
        const float f = key2f(key[e]);
        const bool mq = (f < q_lo) || (f > q_hi);
        const bool ms = fabs((double)f - mu) > sd;
        cq += mq; cs += ms;
        if (mq) sq += f;
        if (ms) ss += f;
    }
    {
        double a = sq, c = ss;
        int ai = cq, ci = cs;
        #pragma unroll
        for (int off = 32; off; off >>= 1) {
            a += __shfl_down(a, off); c += __shfl_down(c, off);
            ai += __shfl_down(ai, off); ci += __shfl_down(ci, off);
        }
        if (lane == 0) { dred[wv] = a; dred[8 + wv] = c; ired[wv] = ai; ired[8 + wv] = ci; }
    }
    __syncthreads();
    double sq_t = 0.0, ss_t = 0.0;
    int cq_t = 0, cs_t = 0;
    for (int k = 0; k < 8; ++k) {
        sq_t += dred[k]; ss_t += dred[8 + k];
        cq_t += ired[k]; cs_t += ired[8 + k];
    }

    int mode;                 // 0 = quantile mask, 1 = simple, 2 = all
    double cnt_sel, sum_sel;
    if (cq_t > 0)      { mode = 0; cnt_sel = cq_t; sum_sel = sq_t; }
    else if (cs_t > 0) { mode = 1; cnt_sel = cs_t; sum_sel = ss_t; }
    else               { mode = 2; cnt_sel = NRES; sum_sel = S; }
    const double mean_w = sum_sel / cnt_sel;
    __syncthreads();

    // Pass C: masked unbiased variance
    double acc = 0.0;
    #pragma unroll
    for (int e = 0; e < 24; ++e) {
        const float f = key2f(key[e]);
        bool w;
        if (mode == 0)      w = (f < q_lo) || (f > q_hi);
        else if (mode == 1) w = fabs((double)f - mu) > sd;
        else                w = true;
        if (w) { const double d = (double)f - mean_w; acc += d * d; }
    }
    {
        double a = acc;
        #pragma unroll
        for (int off = 32; off; off >>= 1) a += __shfl_down(a, off);
        if (lane == 0) dred[wv] = a;
    }
    __syncthreads();
    double acc_t = 0.0;
    for (int k = 0; k < 8; ++k) acc_t += dred[k];
    if (tid == 0) sig[pair] = (float)sqrt(acc_t / (cnt_sel - 1.0));
}

// ---------------------------------------------------------------------------
// Kernel 4: out = mean_b max(sig[2b], sig[2b+1])
// ---------------------------------------------------------------------------
__global__ void final_kernel(const float* __restrict__ sig, float* __restrict__ out) {
    const int lane = threadIdx.x;
    float m = 0.f;
    if (lane < NB) m = fmaxf(sig[2 * lane], sig[2 * lane + 1]);
    #pragma unroll
    for (int off = 8; off; off >>= 1) m += __shfl_down(m, off);
    if (lane == 0) out[0] = m / (float)NB;
}

extern "C" void kernel_launch(void* const* d_in, const int* in_sizes, int n_in,
                              void* d_out, int out_size, void* d_ws, size_t ws_size,
                              hipStream_t stream) {
    const float* x = (const float*)d_in[0];
    const float* y = (const float*)d_in[1];
    char* w = (char*)d_ws;
    float4*   arrA     = (float4*)(w);                        // 2 MB
    uint32_t* keys     = (uint32_t*)(w + 2097152);            // 1.5 MB
    uint32_t* histg    = (uint32_t*)(w + 3670016);            // 256 KB
    double*   partials = (double*)(w + 3932160);              // 8 KB
    float*    sig      = (float*)(w + 3940352);               // 128 B
    u16*      starts   = (u16*)(w + 3940480);                 // 260 KB
    u16*      idx16    = (u16*)(w + 4206720);                 // 256 KB

    hipMemsetAsync(histg, 0, (size_t)NPAIR * 2048 * 4, stream);
    build_kernel<<<NPAIR, 256, 0, stream>>>(x, y, arrA, starts, idx16);
    query_kernel<<<dim3(NPTS / 256, NPAIR), 256, 0, stream>>>(arrA, starts, idx16,
                                                              keys, histg, partials);
    sigma_kernel<<<NPAIR, STH, 0, stream>>>(keys, histg, partials, sig);
    final_kernel<<<1, 64, 0, stream>>>(sig, (float*)d_out);
}

// Round 6
// 131.864 us; speedup vs baseline: 1.1134x; 1.1134x over previous
//
#include <hip/hip_runtime.h>
#include <stdint.h>
#include <math.h>

typedef unsigned short u16;
typedef unsigned long long ull;

// Problem constants (B=16, N=M=4096, D=3)
#define NPTS  4096
#define NB    16
#define NRES  12288               // residuals per (batch, direction)
#define NPAIR 32                  // 16 batches x 2 directions
#define G     16                  // grid cells per axis
#define NCELL 4096                // G^3
#define HCEL  0.0625f             // 1/G
#define SSTR  4160                // starts stride (u16 elems, >= 4097)
#define MARGIN 1e-5f
// 0-indexed order-statistic ranks for jnp.quantile(0.15/0.85, linear)
#define RANK_LO 1843u
#define RANK_HI 10443u

__device__ __forceinline__ uint32_t f2key(float f) {
    uint32_t u = __float_as_uint(f);
    return (u & 0x80000000u) ? ~u : (u | 0x80000000u);
}
__device__ __forceinline__ float key2f(uint32_t k) {
    uint32_t u = (k & 0x80000000u) ? (k ^ 0x80000000u) : ~k;
    return __uint_as_float(u);
}

// ---------------------------------------------------------------------------
// Kernel 1: build — counting-sort targets into 16^3 cells. 32 blocks x 1024.
// Also zeroes this pd's slice of the global level-1 histogram (histg).
// ---------------------------------------------------------------------------
__global__ __launch_bounds__(1024) void build_kernel(const float* __restrict__ x,
                                                     const float* __restrict__ y,
                                                     float4* __restrict__ arrA,
                                                     u16* __restrict__ starts,
                                                     u16* __restrict__ idx16,
                                                     uint32_t* __restrict__ histg) {
    __shared__ uint32_t hist[NCELL];          // 16 KB
    __shared__ uint32_t wpart[16];
    const int pd = blockIdx.x, b = pd >> 1, dir = pd & 1;
    const float* t = (dir == 0 ? y : x) + (size_t)b * NPTS * 3;
    const int tid = threadIdx.x, lane = tid & 63, wv = tid >> 6;

    #pragma unroll
    for (int j = 0; j < 4; ++j) hist[tid * 4 + j] = 0u;
    histg[(size_t)pd * 2048 + tid * 2 + 0] = 0u;
    histg[(size_t)pd * 2048 + tid * 2 + 1] = 0u;
    __syncthreads();

    // phase 1: 4 targets/thread (12 floats = 3 aligned float4 loads)
    float f[12];
    int ci[4];
    {
        const float4* tp = reinterpret_cast<const float4*>(t + (size_t)tid * 12);
        #pragma unroll
        for (int j = 0; j < 3; ++j) {
            const float4 v = tp[j];
            f[j * 4 + 0] = v.x; f[j * 4 + 1] = v.y; f[j * 4 + 2] = v.z; f[j * 4 + 3] = v.w;
        }
        #pragma unroll
        for (int k = 0; k < 4; ++k) {
            const int cx = (int)(f[k * 3 + 0] * 16.f);
            const int cy = (int)(f[k * 3 + 1] * 16.f);
            const int cz = (int)(f[k * 3 + 2] * 16.f);
            ci[k] = (cx * G + cy) * G + cz;
            atomicAdd(&hist[ci[k]], 1u);
        }
    }
    __syncthreads();

    // phase 2: exclusive scan of 4096 bins (4/thread, 16 waves)
    {
        uint32_t loc[4], sum = 0;
        const int base = tid * 4;
        #pragma unroll
        for (int j = 0; j < 4; ++j) { loc[j] = hist[base + j]; sum += loc[j]; }
        uint32_t sc = sum;
        #pragma unroll
        for (int off = 1; off < 64; off <<= 1) {
            const uint32_t u = __shfl_up(sc, off);
            if (lane >= off) sc += u;
        }
        if (lane == 63) wpart[wv] = sc;
        __syncthreads();
        uint32_t wbase = 0;
        #pragma unroll
        for (int k = 0; k < 16; ++k) wbase += (k < wv) ? wpart[k] : 0u;
        uint32_t ex = wbase + sc - sum;
        #pragma unroll
        for (int j = 0; j < 4; ++j) { hist[base + j] = ex; ex += loc[j]; }
    }
    __syncthreads();

    // starts (exclusive prefix; entry [4096] = total)
    for (int i = tid; i <= NCELL; i += 1024)
        starts[(size_t)pd * SSTR + i] = (u16)((i == NCELL) ? NPTS : hist[i]);
    __syncthreads();

    // phase 3: scatter (order within cell arbitrary; ties use idx16)
    #pragma unroll
    for (int k = 0; k < 4; ++k) {
        const float px = f[k * 3 + 0], py = f[k * 3 + 1], pz = f[k * 3 + 2];
        const uint32_t pos = atomicAdd(&hist[ci[k]], 1u);
        const float w = fmaf(pz, pz, fmaf(py, py, px * px));
        arrA[(size_t)pd * NPTS + pos] = make_float4(-2.f * px, -2.f * py, -2.f * pz, w);
        idx16[(size_t)pd * NPTS + pos] = (u16)(tid * 4 + k);
    }
}

// ---------------------------------------------------------------------------
// Kernel 2: grid NN, 4 lanes per query. grid=(64 qblocks, 32 pairdirs) x 256.
// Quad lanes stride candidate runs by 4; packed u64 min-reduce preserves
// first-original-index tie semantics. 27-cell phase fully unrolled with
// clamped (possibly duplicate) runs so all run bounds load up front.
// ---------------------------------------------------------------------------
__global__ __launch_bounds__(256, 4) void query_kernel(const float4* __restrict__ arrA,
                                                       const u16* __restrict__ starts,
                                                       const u16* __restrict__ idx16,
                                                       uint32_t* __restrict__ keys,
                                                       uint32_t* __restrict__ histg,
                                                       double* __restrict__ partials) {
    __shared__ double wred[8];
    const int pd = blockIdx.y;
    const int tid = threadIdx.x, lane = tid & 63, wv = tid >> 6;
    const int l4 = tid & 3;
    const int p = blockIdx.x * 64 + (tid >> 2);   // sorted query position

    const float4* __restrict__ tp = arrA + (size_t)pd * NPTS;
    const u16* __restrict__ st = starts + (size_t)pd * SSTR;
    const u16* __restrict__ ixp = idx16 + (size_t)pd * NPTS;

    const float4 Q = arrA[(size_t)(pd ^ 1) * NPTS + p];
    const float qx = -0.5f * Q.x, qy = -0.5f * Q.y, qz = -0.5f * Q.z;
    const float qq = Q.w;                         // |q|^2 (shell bound only)
    const int cx = (int)(qx * 16.f), cy = (int)(qy * 16.f), cz = (int)(qz * 16.f);

    float best = 3.0e38f;
    ull pk = ~0ull;

    #define SCAN_RUN(A_, E_)                                                        \
        for (int p2 = (A_) + l4; p2 < (E_); p2 += 4) {                              \
            const float4 T = tp[p2];                                                \
            const float d = fmaf(qx, T.x, fmaf(qy, T.y, fmaf(qz, T.z, T.w)));       \
            best = fminf(best, d);                                                  \
            const ull cand = ((ull)f2key(d) << 32) |                                \
                             ((ull)ixp[p2] << 16) | (uint32_t)p2;                   \
            pk = (cand < pk) ? cand : pk;                                           \
        }

    {   // Chebyshev <=1: 9 clamped z-runs (duplicates at borders are harmless)
        const int zlo = max(cz - 1, 0), zhi = min(cz + 1, G - 1);
        int a9[9], e9[9];
        #pragma unroll
        for (int r = 0; r < 9; ++r) {
            const int ix = min(max(cx + (r / 3) - 1, 0), G - 1);
            const int iy = min(max(cy + (r % 3) - 1, 0), G - 1);
            const int c0 = (ix * G + iy) * G;
            a9[r] = st[c0 + zlo];
            e9[r] = st[c0 + zhi + 1];
        }
        #pragma unroll
        for (int r = 0; r < 9; ++r) SCAN_RUN(a9[r], e9[r])
    }

    // expand shells while min possible distance could beat the quad's best
    for (int s = 2; s <= G - 1; ++s) {
        float qb = best;
        qb = fminf(qb, __shfl_xor(qb, 1));
        qb = fminf(qb, __shfl_xor(qb, 2));
        const float dmin = (float)(s - 1) * HCEL;
        if (fmaf(dmin, dmin, -(qb + qq)) > MARGIN) break;
        for (int dx = -s; dx <= s; ++dx) {
            const int ix = cx + dx;
            if (ix < 0 || ix > G - 1) continue;
            const int adx = dx < 0 ? -dx : dx;
            for (int dy = -s; dy <= s; ++dy) {
                const int iy = cy + dy;
                if (iy < 0 || iy > G - 1) continue;
                const int ady = dy < 0 ? -dy : dy;
                const int c0 = (ix * G + iy) * G;
                if (max(adx, ady) == s) {        // full z range
                    const int zlo = max(cz - s, 0), zhi = min(cz + s, G - 1);
                    const int a = st[c0 + zlo], e = st[c0 + zhi + 1];
                    SCAN_RUN(a, e)
                } else {                         // only z = cz +/- s
                    const int z1 = cz - s;
                    if (z1 >= 0) { const int a = st[c0 + z1], e = st[c0 + z1 + 1]; SCAN_RUN(a, e) }
                    const int z2 = cz + s;
                    if (z2 <= G - 1) { const int a = st[c0 + z2], e = st[c0 + z2 + 1]; SCAN_RUN(a, e) }
                }
            }
        }
    }
    #undef SCAN_RUN

    // quad min-reduce of packed (key, orig, pos)
    {
        ull o = __shfl_xor(pk, 1); pk = (o < pk) ? o : pk;
        o = __shfl_xor(pk, 2);     pk = (o < pk) ? o : pk;
    }

    // residuals (exact: -0.5 * (-2t) == t bitwise)
    const int pos = (int)(pk & 0xFFFFu);
    const float4 T = tp[pos];
    const float rx = qx - (-0.5f * T.x);
    const float ry = qy - (-0.5f * T.y);
    const float rz = qz - (-0.5f * T.z);

    if (l4 < 3) {
        const uint32_t kk = (l4 == 0) ? f2key(rx) : ((l4 == 1) ? f2key(ry) : f2key(rz));
        keys[(size_t)pd * NRES + (size_t)p * 3 + l4] = kk;
        atomicAdd(&histg[(size_t)pd * 2048 + (kk >> 21)], 1u);
    }

    // f64 partial sums (lane 0 of quad only)
    double s1 = 0.0, s2 = 0.0;
    if (l4 == 0) {
        s1 = (double)rx + (double)ry + (double)rz;
        s2 = (double)rx * rx + (double)ry * ry + (double)rz * rz;
    }
    #pragma unroll
    for (int off = 32; off; off >>= 1) { s1 += __shfl_down(s1, off); s2 += __shfl_down(s2, off); }
    if (lane == 0) { wred[wv] = s1; wred[4 + wv] = s2; }
    __syncthreads();
    if (tid == 0) {
        double a = 0.0, c = 0.0;
        for (int k = 0; k < 4; ++k) { a += wred[k]; c += wred[4 + k]; }
        partials[(size_t)pd * 128 + blockIdx.x * 2 + 0] = a;
        partials[(size_t)pd * 128 + blockIdx.x * 2 + 1] = c;
    }
}

// ---------------------------------------------------------------------------
// Kernel 3: robust masked std. 32 blocks x 512 threads; keys in registers;
// level-1 hist pre-built; radix levels 2/3 in LDS.
// ---------------------------------------------------------------------------
#define STH 512

__device__ __forceinline__ void scan2048(uint32_t* h, uint32_t* wtmp) {
    const int tid = threadIdx.x, lane = tid & 63, wv = tid >> 6;
    const int i = tid * 4;
    const uint32_t a0 = h[i], a1 = h[i + 1], a2 = h[i + 2], a3 = h[i + 3];
    const uint32_t v = a0 + a1 + a2 + a3;
    uint32_t sc = v;
    #pragma unroll
    for (int off = 1; off < 64; off <<= 1) {
        const uint32_t u = __shfl_up(sc, off);
        if (lane >= off) sc += u;
    }
    if (lane == 63) wtmp[wv] = sc;
    __syncthreads();
    uint32_t base = 0;
    #pragma unroll
    for (int k = 0; k < 8; ++k) base += (k < wv) ? wtmp[k] : 0u;
    const uint32_t ex = base + sc - v;
    h[i] = ex; h[i + 1] = ex + a0; h[i + 2] = ex + a0 + a1; h[i + 3] = ex + a0 + a1 + a2;
    __syncthreads();
}

__device__ __forceinline__ int ubin(const uint32_t* cum, int n, uint32_t r) {
    int lo = 0, hi = n - 1;                    // largest b with cum[b] <= r
    while (lo < hi) {
        const int mid = (lo + hi + 1) >> 1;
        if (cum[mid] <= r) lo = mid; else hi = mid - 1;
    }
    return lo;
}

__global__ __launch_bounds__(512) void sigma_kernel(const uint32_t* __restrict__ keysg,
                                                    const uint32_t* __restrict__ histg,
                                                    const double* __restrict__ partials,
                                                    float* __restrict__ sig) {
    __shared__ uint32_t hist[4096];            // 16 KB
    __shared__ uint32_t wtmp[8];
    __shared__ double dred[16];
    __shared__ int ired[16];
    __shared__ uint32_t umin[16];
    __shared__ uint32_t bc[8];

    const int pair = blockIdx.x;
    const int tid = threadIdx.x, lane = tid & 63, wv = tid >> 6;

    // keys into registers (coalesced)
    uint32_t key[24];
    const uint32_t* kp = keysg + (size_t)pair * NRES;
    #pragma unroll
    for (int e = 0; e < 24; ++e) key[e] = kp[e * STH + tid];

    // full sums from f64 partials
    double S = 0.0, S2 = 0.0;
    {
        const double* pp = partials + (size_t)pair * 128;
        for (int k = 0; k < 64; ++k) { S += pp[2 * k]; S2 += pp[2 * k + 1]; }
    }
    const double mu = S / NRES;
    const double var_all = (S2 - S * mu) / (NRES - 1);
    const double sd = sqrt(var_all > 0.0 ? var_all : 0.0);

    // ---- Level 1: load pre-built 11-bit histogram, scan ----
    {
        const uint32_t* hg = histg + (size_t)pair * 2048;
        #pragma unroll
        for (int j = 0; j < 4; ++j) hist[tid * 4 + j] = hg[tid * 4 + j];
    }
    __syncthreads();
    scan2048(hist, wtmp);
    if (tid < 2) {
        const uint32_t r = tid ? RANK_HI : RANK_LO;
        const int bb = ubin(hist, 2048, r);
        bc[tid * 4 + 0] = (uint32_t)bb;
        bc[tid * 4 + 1] = r - hist[bb];
    }
    __syncthreads();

    // ---- Level 2: two concurrent 11-bit histograms ----
    const uint32_t pA1 = bc[0], rA1 = bc[1], pB1 = bc[4], rB1 = bc[5];
    #pragma unroll
    for (int j = 0; j < 8; ++j) hist[tid * 8 + j] = 0u;
    __syncthreads();
    #pragma unroll
    for (int e = 0; e < 24; ++e) {
        const uint32_t k = key[e];
        const uint32_t pfx = k >> 21, bin = (k >> 10) & 2047u;
        if (pfx == pA1) atomicAdd(&hist[bin], 1u);
        if (pfx == pB1) atomicAdd(&hist[2048 + bin], 1u);
    }
    __syncthreads();
    scan2048(hist, wtmp);
    scan2048(hist + 2048, wtmp);
    if (tid < 2) {
        const uint32_t* h = hist + tid * 2048;
        const uint32_t pfx = tid ? pB1 : pA1;
        const uint32_t r = tid ? rB1 : rA1;
        const int bb = ubin(h, 2048, r);
        bc[tid * 4 + 0] = (pfx << 11) | (uint32_t)bb;
        bc[tid * 4 + 1] = r - h[bb];
    }
    __syncthreads();

    // ---- Level 3: two concurrent 10-bit histograms -> exact keys ----
    const uint32_t pA2 = bc[0], rA2 = bc[1], pB2 = bc[4], rB2 = bc[5];
    #pragma unroll
    for (int j = 0; j < 8; ++j) hist[tid * 8 + j] = 0u;
    __syncthreads();
    #pragma unroll
    for (int e = 0; e < 24; ++e) {
        const uint32_t k = key[e];
        if ((k >> 10) == pA2) atomicAdd(&hist[k & 1023u], 1u);
        if ((k >> 10) == pB2) atomicAdd(&hist[2048 + (k & 1023u)], 1u);
    }
    __syncthreads();
    scan2048(hist, wtmp);
    scan2048(hist + 2048, wtmp);
    if (tid < 2) {
        const uint32_t* h = hist + tid * 2048;
        const uint32_t pfx = tid ? pB2 : pA2;
        const uint32_t r = tid ? rB2 : rA2;
        const uint32_t rtot = tid ? RANK_HI : RANK_LO;
        const int bb = ubin(h, 1024, r);
        const uint32_t k0 = (pfx << 10) | (uint32_t)bb;
        const uint32_t abs_le = (rtot - r) + h[bb + 1];
        bc[tid * 4 + 0] = k0;
        bc[tid * 4 + 1] = (abs_le >= rtot + 2u) ? 1u : 0u;   // rank+1 shares key?
    }
    __syncthreads();

    // ---- rank+1 keys: duplicate-covered or min key strictly greater ----
    const uint32_t k0 = bc[0], dup1 = bc[1], k2 = bc[4], dup3 = bc[5];
    uint32_t m1 = 0xFFFFFFFFu, m3 = 0xFFFFFFFFu;
    #pragma unroll
    for (int e = 0; e < 24; ++e) {
        const uint32_t k = key[e];
        if (k > k0 && k < m1) m1 = k;
        if (k > k2 && k < m3) m3 = k;
    }
    {
        uint32_t a = m1, c = m3;
        #pragma unroll
        for (int off = 32; off; off >>= 1) {
            const uint32_t ua = __shfl_down(a, off), uc = __shfl_down(c, off);
            a = (ua < a) ? ua : a; c = (uc < c) ? uc : c;
        }
        if (lane == 0) { umin[wv] = a; umin[8 + wv] = c; }
    }
    __syncthreads();
    uint32_t m1r = 0xFFFFFFFFu, m3r = 0xFFFFFFFFu;
    for (int k = 0; k < 8; ++k) {
        m1r = (umin[k] < m1r) ? umin[k] : m1r;
        m3r = (umin[8 + k] < m3r) ? umin[8 + k] : m3r;
    }
    const uint32_t k1 = dup1 ? k0 : m1r;
    const uint32_t k3 = dup3 ? k2 : m3r;

    // Linear-interpolated quantiles
    const double vl0 = (double)key2f(k0), vl1 = (double)key2f(k1);
    const double vh0 = (double)key2f(k2), vh1 = (double)key2f(k3);
    const double fr_lo = 0.15 * (NRES - 1) - (double)RANK_LO;
    const double fr_hi = 0.85 * (NRES - 1) - (double)RANK_HI;
    const float q_lo = (float)(vl0 + fr_lo * (vl1 - vl0));
    const float q_hi = (float)(vh0 + fr_hi * (vh1 - vh0));

    // Pass B: counts + sums under both predicates
    int cq = 0, cs = 0;
    double sq = 0.0, ss = 0.0;
    #pragma unroll
    for (int e = 0; e < 24; ++e) {
        const float f = key2f(key[e]);
        const bool mq = (f < q_lo) || (f > q_hi);
        const bool ms = fabs((double)f - mu) > sd;
        cq += mq; cs += ms;
        if (mq) sq += f;
        if (ms) ss += f;
    }
    {
        double a = sq, c = ss;
        int ai = cq, ci = cs;
        #pragma unroll
        for (int off = 32; off; off >>= 1) {
            a += __shfl_down(a, off); c += __shfl_down(c, off);
            ai += __shfl_down(ai, off); ci += __shfl_down(ci, off);
        }
        if (lane == 0) { dred[wv] = a; dred[8 + wv] = c; ired[wv] = ai; ired[8 + wv] = ci; }
    }
    __syncthreads();
    double sq_t = 0.0, ss_t = 0.0;
    int cq_t = 0, cs_t = 0;
    for (int k = 0; k < 8; ++k) {
        sq_t += dred[k]; ss_t += dred[8 + k];
        cq_t += ired[k]; cs_t += ired[8 + k];
    }

    int mode;                 // 0 = quantile mask, 1 = simple, 2 = all
    double cnt_sel, sum_sel;
    if (cq_t > 0)      { mode = 0; cnt_sel = cq_t; sum_sel = sq_t; }
    else if (cs_t > 0) { mode = 1; cnt_sel = cs_t; sum_sel = ss_t; }
    else               { mode = 2; cnt_sel = NRES; sum_sel = S; }
    const double mean_w = sum_sel / cnt_sel;
    __syncthreads();

    // Pass C: masked unbiased variance
    double acc = 0.0;
    #pragma unroll
    for (int e = 0; e < 24; ++e) {
        const float f = key2f(key[e]);
        bool w;
        if (mode == 0)      w = (f < q_lo) || (f > q_hi);
        else if (mode == 1) w = fabs((double)f - mu) > sd;
        else                w = true;
        if (w) { const double d = (double)f - mean_w; acc += d * d; }
    }
    {
        double a = acc;
        #pragma unroll
        for (int off = 32; off; off >>= 1) a += __shfl_down(a, off);
        if (lane == 0) dred[wv] = a;
    }
    __syncthreads();
    double acc_t = 0.0;
    for (int k = 0; k < 8; ++k) acc_t += dred[k];
    if (tid == 0) sig[pair] = (float)sqrt(acc_t / (cnt_sel - 1.0));
}

// ---------------------------------------------------------------------------
// Kernel 4: out = mean_b max(sig[2b], sig[2b+1])
// ---------------------------------------------------------------------------
__global__ void final_kernel(const float* __restrict__ sig, float* __restrict__ out) {
    const int lane = threadIdx.x;
    float m = 0.f;
    if (lane < NB) m = fmaxf(sig[2 * lane], sig[2 * lane + 1]);
    #pragma unroll
    for (int off = 8; off; off >>= 1) m += __shfl_down(m, off);
    if (lane == 0) out[0] = m / (float)NB;
}

extern "C" void kernel_launch(void* const* d_in, const int* in_sizes, int n_in,
                              void* d_out, int out_size, void* d_ws, size_t ws_size,
                              hipStream_t stream) {
    const float* x = (const float*)d_in[0];
    const float* y = (const float*)d_in[1];
    char* w = (char*)d_ws;
    float4*   arrA     = (float4*)(w);                        // 2 MB
    uint32_t* keys     = (uint32_t*)(w + 2097152);            // 1.5 MB
    uint32_t* histg    = (uint32_t*)(w + 3670016);            // 256 KB
    double*   partials = (double*)(w + 3932160);              // 32 KB
    float*    sig      = (float*)(w + 3964928);               // 128 B
    u16*      starts   = (u16*)(w + 3965056);                 // 260 KB
    u16*      idx16    = (u16*)(w + 4231296);                 // 256 KB

    build_kernel<<<NPAIR, 1024, 0, stream>>>(x, y, arrA, starts, idx16, histg);
    query_kernel<<<dim3(64, NPAIR), 256, 0, stream>>>(arrA, starts, idx16,
                                                      keys, histg, partials);
    sigma_kernel<<<NPAIR, STH, 0, stream>>>(keys, histg, partials, sig);
    final_kernel<<<1, 64, 0, stream>>>(sig, (float*)d_out);
}